// Round 5
// baseline (3305.806 us; speedup 1.0000x reference)
//
#include <hip/hip_runtime.h>
#include <hip/hip_fp16.h>
#include <cstddef>
#include <cstdint>

#define BB 16384
#define DIMG 2048
#define HH 512
#define VOCAB 200
#define TT 20

using frag16 = __attribute__((ext_vector_type(8))) short;   // 8 x bf16 (4 VGPRs)
using f32x4v = __attribute__((ext_vector_type(4))) float;   // MFMA accumulator

#define MFMA16(a, b, c) __builtin_amdgcn_mfma_f32_16x16x32_bf16((a), (b), (c), 0, 0, 0)

__device__ __forceinline__ float bf2f(unsigned short u) {
    union { unsigned int i; float f; } c; c.i = ((unsigned int)u) << 16; return c.f;
}
__device__ __forceinline__ unsigned short f2bf(float f) {
    union { float f; unsigned int i; } c; c.f = f;
    unsigned int u = c.i;
    u = (u + 0x7FFFu + ((u >> 16) & 1u)) >> 16;   // RTNE
    return (unsigned short)u;
}
__device__ __forceinline__ float sigf(float x) { return 1.f / (1.f + __expf(-x)); }
__device__ __forceinline__ float ftanh(float x) {
    return 1.f - 2.f / (1.f + __expf(2.f * x));
}
__device__ __forceinline__ void gload16(const void* g, void* l) {
    __builtin_amdgcn_global_load_lds(
        (__attribute__((address_space(1))) void*)g,
        (__attribute__((address_space(3))) void*)l, 16, 0, 0);
}

// ---------------------------------------------------------------------------
// bf16 MFMA GEMM for encoder: C = act(A[M,K] @ W[N,K]^T + bias).
// OM: 0=f32, 1=bf16, 2=f16 output.
// ---------------------------------------------------------------------------
template<int ACT, int OM>
__global__ __launch_bounds__(256) void gemm_bt_mfma(
    const unsigned short* __restrict__ A, const unsigned short* __restrict__ W,
    const float* __restrict__ bias, void* __restrict__ Cv, int M, int N, int K)
{
    __shared__ unsigned short As[128 * 32];
    __shared__ unsigned short Ws[128 * 32];
    const int t = threadIdx.x;
    const int lane = t & 63, w = t >> 6;
    const int bm = blockIdx.x, bn = blockIdx.y;
    const int wm = (w >> 1) * 64, wn = (w & 1) * 64;

    f32x4v acc[4][4];
    #pragma unroll
    for (int i = 0; i < 4; ++i)
        #pragma unroll
        for (int j = 0; j < 4; ++j)
            #pragma unroll
            for (int r = 0; r < 4; ++r) acc[i][j][r] = 0.f;

    const unsigned short* Ag  = A + (size_t)(bm * 128 + (t >> 2)) * K + (t & 3) * 8;
    const unsigned short* Ag2 = A + (size_t)(bm * 128 + 64 + (t >> 2)) * K + (t & 3) * 8;
    const unsigned short* Wg  = W + (size_t)(bn * 128 + (t >> 2)) * K + (t & 3) * 8;
    const unsigned short* Wg2 = W + (size_t)(bn * 128 + 64 + (t >> 2)) * K + (t & 3) * 8;
    char* AsB = (char*)As; char* WsB = (char*)Ws;

    const int kIters = K >> 5;
    for (int ki = 0; ki < kIters; ++ki) {
        const int k0 = ki * 32;
        gload16(Ag  + k0, AsB + w * 1024);
        gload16(Ag2 + k0, AsB + 4096 + w * 1024);
        gload16(Wg  + k0, WsB + w * 1024);
        gload16(Wg2 + k0, WsB + 4096 + w * 1024);
        __syncthreads();
        frag16 af[4], bf[4];
        #pragma unroll
        for (int i = 0; i < 4; ++i) {
            af[i] = *(const frag16*)(AsB + (wm + i * 16 + (lane & 15)) * 64 + (lane >> 4) * 16);
            bf[i] = *(const frag16*)(WsB + (wn + i * 16 + (lane & 15)) * 64 + (lane >> 4) * 16);
        }
        #pragma unroll
        for (int i = 0; i < 4; ++i)
            #pragma unroll
            for (int j = 0; j < 4; ++j)
                acc[i][j] = MFMA16(af[i], bf[j], acc[i][j]);
        __syncthreads();
    }

    #pragma unroll
    for (int j = 0; j < 4; ++j) {
        const int gn = bn * 128 + wn + j * 16 + (lane & 15);
        const float bv = bias[gn];
        #pragma unroll
        for (int i = 0; i < 4; ++i) {
            #pragma unroll
            for (int r = 0; r < 4; ++r) {
                const size_t gm = (size_t)(bm * 128 + wm + i * 16 + (lane >> 4) * 4 + r);
                float v = acc[i][j][r] + bv;
                if (ACT == 1) v = fmaxf(v, 0.f);
                if (OM == 0)      ((float*)Cv)[gm * N + gn] = v;
                else if (OM == 1) ((unsigned short*)Cv)[gm * N + gn] = f2bf(v);
                else              ((__half*)Cv)[gm * N + gn] = __float2half(v);
            }
        }
    }
}

// ---------------------------------------------------------------------------
// Persistent GRU+heads kernel. Grid 256 x 512 threads (1 block/CU, 8 waves).
// h [64 rows x 512] lives in LDS (bf16, MFMA-fragment-linear layout) across
// all 20 steps; never touches global memory.
//   LDS layout: frag-block (bt, kc) at byte (bt*16+kc)*1024; within a block,
//   lane slot l = q*16+m holds h[bt*16+m][kc*32 + q*8 .. +8) (16 B).
// Per step: GRU GEMM (B-frags = h from LDS, A-frags = whh direct from L2,
// no barriers in K-loop), gate math in regs (h_new held in VGPRs), one
// barrier, h write-back, then fused heads (u1/u2 via small global scratch).
// ---------------------------------------------------------------------------
__global__ __launch_bounds__(512, 2) void persistent_gru(
    const __half* __restrict__ xg,            // [B,3H] fp16
    const unsigned short* __restrict__ whhb,  // [3H,H] bf16
    const float* __restrict__ bhh,            // [3H]
    const unsigned short* __restrict__ w1c,   // [128,512] bf16
    const unsigned short* __restrict__ w2s,   // [128,64]
    const unsigned short* __restrict__ w3s,   // [208,64]
    const float* __restrict__ b1c, const float* __restrict__ b2c,
    const float* __restrict__ b3s,
    const float* __restrict__ cw3, const float* __restrict__ cb3,
    const int* __restrict__ actions,
    unsigned short* __restrict__ u1g,         // [B,128] bf16 scratch
    unsigned short* __restrict__ u2g,         // [B,128] bf16 scratch
    float* __restrict__ out_lp, float* __restrict__ out_ent,
    float* __restrict__ out_v)
{
    __shared__ unsigned short hlds[32768];    // 64 KB exactly
    char* hb = (char*)hlds;
    const int t = threadIdx.x;
    const int w = t >> 6, lane = t & 63;
    const int q = lane >> 4, m = lane & 15;
    const int row0 = blockIdx.x * 64;

    // h0 = 0
    {
        uint4 z = make_uint4(0u, 0u, 0u, 0u);
        #pragma unroll
        for (int i = 0; i < 8; ++i)
            *(uint4*)(hb + i * 8192 + t * 16) = z;
    }
    __syncthreads();

    const __half* xgb = xg + (size_t)row0 * (3 * HH);
    unsigned short* u1b = u1g + (size_t)row0 * 128;
    unsigned short* u2b = u2g + (size_t)row0 * 128;

    for (int ts = 0; ts < TT; ++ts) {
        // ============ GRU: wave w owns hcols [w*64, (w+1)*64) ============
        uint2 hnew[4][4];
        #pragma unroll
        for (int g = 0; g < 4; ++g) {
            const int hcb = w * 64 + g * 16;
            f32x4v acc[3][4];
            #pragma unroll
            for (int ga = 0; ga < 3; ++ga)
                #pragma unroll
                for (int bt = 0; bt < 4; ++bt)
                    #pragma unroll
                    for (int r = 0; r < 4; ++r) acc[ga][bt][r] = 0.f;

            const unsigned short* wp = whhb + (size_t)(hcb + m) * HH + q * 8;
            #pragma unroll 4
            for (int kc = 0; kc < 16; ++kc) {
                frag16 af0 = *(const frag16*)(wp + kc * 32);
                frag16 af1 = *(const frag16*)(wp + (size_t)HH * HH + kc * 32);
                frag16 af2 = *(const frag16*)(wp + (size_t)2 * HH * HH + kc * 32);
                #pragma unroll
                for (int bt = 0; bt < 4; ++bt) {
                    frag16 bf = *(const frag16*)(hb + (bt * 16 + kc) * 1024 + lane * 16);
                    acc[0][bt] = MFMA16(af0, bf, acc[0][bt]);
                    acc[1][bt] = MFMA16(af1, bf, acc[1][bt]);
                    acc[2][bt] = MFMA16(af2, bf, acc[2][bt]);
                }
            }
            // gate math; lane holds hcols hcb+q*4..+3 for batch bt*16+m
            const float4 br4 = *(const float4*)&bhh[hcb + q * 4];
            const float4 bz4 = *(const float4*)&bhh[HH + hcb + q * 4];
            const float4 bn4 = *(const float4*)&bhh[2 * HH + hcb + q * 4];
            const float brr[4] = {br4.x, br4.y, br4.z, br4.w};
            const float bzz[4] = {bz4.x, bz4.y, bz4.z, bz4.w};
            const float bnn[4] = {bn4.x, bn4.y, bn4.z, bn4.w};
            const int kch = w * 2 + (g >> 1);
            const int qa  = (g * 2 + (q >> 1)) & 3;
            const int eoff = (q & 1) * 8;
            #pragma unroll
            for (int bt = 0; bt < 4; ++bt) {
                const int row = bt * 16 + m;
                const __half* xp = xgb + (size_t)row * (3 * HH) + hcb + q * 4;
                float2 xr0 = __half22float2(*(const __half2*)(xp));
                float2 xr1 = __half22float2(*(const __half2*)(xp + 2));
                float2 xz0 = __half22float2(*(const __half2*)(xp + HH));
                float2 xz1 = __half22float2(*(const __half2*)(xp + HH + 2));
                float2 xn0 = __half22float2(*(const __half2*)(xp + 2 * HH));
                float2 xn1 = __half22float2(*(const __half2*)(xp + 2 * HH + 2));
                const float xr[4] = {xr0.x, xr0.y, xr1.x, xr1.y};
                const float xz[4] = {xz0.x, xz0.y, xz1.x, xz1.y};
                const float xn[4] = {xn0.x, xn0.y, xn1.x, xn1.y};
                uint2 hold = *(const uint2*)(hb + (bt * 16 + kch) * 1024 + (qa * 16 + m) * 16 + eoff);
                const float ho[4] = { bf2f((unsigned short)(hold.x & 0xFFFF)),
                                      bf2f((unsigned short)(hold.x >> 16)),
                                      bf2f((unsigned short)(hold.y & 0xFFFF)),
                                      bf2f((unsigned short)(hold.y >> 16)) };
                unsigned short hv[4];
                #pragma unroll
                for (int r = 0; r < 4; ++r) {
                    float rg = sigf(xr[r] + acc[0][bt][r] + brr[r]);
                    float zg = sigf(xz[r] + acc[1][bt][r] + bzz[r]);
                    float ng = tanhf(xn[r] + rg * (acc[2][bt][r] + bnn[r]));
                    hv[r] = f2bf((1.f - zg) * ng + zg * ho[r]);
                }
                hnew[g][bt].x = (unsigned)hv[0] | ((unsigned)hv[1] << 16);
                hnew[g][bt].y = (unsigned)hv[2] | ((unsigned)hv[3] << 16);
            }
        }
        __syncthreads();   // all waves done reading old h
        #pragma unroll
        for (int g = 0; g < 4; ++g) {
            const int kch = w * 2 + (g >> 1);
            const int qa  = (g * 2 + (q >> 1)) & 3;
            const int eoff = (q & 1) * 8;
            #pragma unroll
            for (int bt = 0; bt < 4; ++bt)
                *(uint2*)(hb + (bt * 16 + kch) * 1024 + (qa * 16 + m) * 16 + eoff) = hnew[g][bt];
        }
        __syncthreads();   // h_t visible to all waves

        // ============ heads phase 1: u1 = tanh(h @ w1c^T + b1c) ============
        // D[headcol][batch]: A = w1c rows (wave w owns headcol tile w), B = h.
        {
            f32x4v a1[4];
            #pragma unroll
            for (int bt = 0; bt < 4; ++bt)
                #pragma unroll
                for (int r = 0; r < 4; ++r) a1[bt][r] = 0.f;
            const unsigned short* wp = w1c + (size_t)(w * 16 + m) * HH + q * 8;
            #pragma unroll 4
            for (int kc = 0; kc < 16; ++kc) {
                frag16 af = *(const frag16*)(wp + kc * 32);
                #pragma unroll
                for (int bt = 0; bt < 4; ++bt) {
                    frag16 bf = *(const frag16*)(hb + (bt * 16 + kc) * 1024 + lane * 16);
                    a1[bt] = MFMA16(af, bf, a1[bt]);
                }
            }
            const float4 b14 = *(const float4*)&b1c[w * 16 + q * 4];
            const float bb[4] = {b14.x, b14.y, b14.z, b14.w};
            #pragma unroll
            for (int bt = 0; bt < 4; ++bt) {
                unsigned short v[4];
                #pragma unroll
                for (int r = 0; r < 4; ++r) v[r] = f2bf(ftanh(a1[bt][r] + bb[r]));
                uint2 pk;
                pk.x = (unsigned)v[0] | ((unsigned)v[1] << 16);
                pk.y = (unsigned)v[2] | ((unsigned)v[3] << 16);
                *(uint2*)(u1b + (size_t)(bt * 16 + m) * 128 + w * 16 + q * 4) = pk;
            }
        }
        __syncthreads();

        // ============ phase 2: u2 (actor tiles 0-3, critic 4-7) ============
        {
            f32x4v a2[4];
            #pragma unroll
            for (int bt = 0; bt < 4; ++bt)
                #pragma unroll
                for (int r = 0; r < 4; ++r) a2[bt][r] = 0.f;
            const int koff = (w >> 2) * 64;
            const unsigned short* wp = w2s + (size_t)(w * 16 + m) * 64 + q * 8;
            #pragma unroll
            for (int kc = 0; kc < 2; ++kc) {
                frag16 af = *(const frag16*)(wp + kc * 32);
                #pragma unroll
                for (int bt = 0; bt < 4; ++bt) {
                    frag16 bf = *(const frag16*)(u1b + (size_t)(bt * 16 + m) * 128 + koff + kc * 32 + q * 8);
                    a2[bt] = MFMA16(af, bf, a2[bt]);
                }
            }
            const float4 b24 = *(const float4*)&b2c[w * 16 + q * 4];
            const float bb[4] = {b24.x, b24.y, b24.z, b24.w};
            #pragma unroll
            for (int bt = 0; bt < 4; ++bt) {
                unsigned short v[4];
                #pragma unroll
                for (int r = 0; r < 4; ++r) v[r] = f2bf(ftanh(a2[bt][r] + bb[r]));
                uint2 pk;
                pk.x = (unsigned)v[0] | ((unsigned)v[1] << 16);
                pk.y = (unsigned)v[2] | ((unsigned)v[3] << 16);
                *(uint2*)(u2b + (size_t)(bt * 16 + m) * 128 + w * 16 + q * 4) = pk;
            }
        }
        __syncthreads();

        // ============ phase 3: logits+softmax (waves 0-3), value (4-7) ============
        if (w < 4) {
            f32x4v a3[13];
            #pragma unroll
            for (int j = 0; j < 13; ++j)
                #pragma unroll
                for (int r = 0; r < 4; ++r) a3[j][r] = 0.f;
            #pragma unroll
            for (int kc = 0; kc < 2; ++kc) {
                frag16 af = *(const frag16*)(u2b + (size_t)(w * 16 + m) * 128 + kc * 32 + q * 8);
                #pragma unroll
                for (int j = 0; j < 13; ++j) {
                    frag16 bf = *(const frag16*)(w3s + (size_t)(j * 16 + m) * 64 + kc * 32 + q * 8);
                    a3[j] = MFMA16(af, bf, a3[j]);
                }
            }
            float bcol[13];
            #pragma unroll
            for (int j = 0; j < 13; ++j) bcol[j] = b3s[j * 16 + m];
            const bool vlast = (m < 8);
            #pragma unroll
            for (int r = 0; r < 4; ++r) {
                const int gr = row0 + w * 16 + 4 * q + r;
                const int a = actions[(size_t)gr * TT + ts];
                float lg[13], mx = -1e30f;
                #pragma unroll
                for (int j = 0; j < 13; ++j) {
                    float v = a3[j][r] + bcol[j];
                    lg[j] = (j < 12 || vlast) ? v : -1e30f;
                    mx = fmaxf(mx, lg[j]);
                }
                #pragma unroll
                for (int o = 1; o < 16; o <<= 1) mx = fmaxf(mx, __shfl_xor(mx, o));
                float s1 = 0.f, s2 = 0.f, sel = 0.f;
                #pragma unroll
                for (int j = 0; j < 13; ++j) {
                    float e = __expf(lg[j] - mx);
                    s1 += e; s2 += e * lg[j];
                    sel += (j * 16 + m == a) ? lg[j] : 0.f;
                }
                #pragma unroll
                for (int o = 1; o < 16; o <<= 1) {
                    s1 += __shfl_xor(s1, o); s2 += __shfl_xor(s2, o); sel += __shfl_xor(sel, o);
                }
                const float lse = mx + __logf(s1);
                if (m == 0) {
                    out_lp[(size_t)gr * TT + ts]  = sel - lse;
                    out_ent[(size_t)gr * TT + ts] = lse - s2 / s1;
                }
            }
        } else {
            const int row = (w - 4) * 16 + m;
            const unsigned short* ur = u2b + (size_t)row * 128 + 64 + q * 16;
            float pv = 0.f;
            #pragma unroll
            for (int kk = 0; kk < 16; ++kk)
                pv += bf2f(ur[kk]) * cw3[q * 16 + kk];
            pv += __shfl_xor(pv, 16);
            pv += __shfl_xor(pv, 32);
            if (q == 0) out_v[(size_t)(row0 + row) * TT + ts] = pv + cb3[0];
        }
        // next iteration's first barrier orders everything; u1/u2 reuse is safe
        // because no wave writes u1 until all waves pass the next h-write barrier.
    }
}

// ---------------------------------------------------------------------------
// One-time packing of head weights/biases.
// ---------------------------------------------------------------------------
__global__ void prep_heads(
    const float* __restrict__ aw1, const float* __restrict__ cw1,
    const float* __restrict__ aw2, const float* __restrict__ cw2,
    const float* __restrict__ aw3,
    const float* __restrict__ ab1, const float* __restrict__ cb1,
    const float* __restrict__ ab2, const float* __restrict__ cb2,
    const float* __restrict__ ab3,
    unsigned short* __restrict__ w1c, unsigned short* __restrict__ w2s,
    unsigned short* __restrict__ w3s,
    float* __restrict__ b1c, float* __restrict__ b2c, float* __restrict__ b3s)
{
    int i = blockIdx.x * 256 + threadIdx.x;
    if (i < 65536) { int r = i >> 9, c = i & 511;
        w1c[i] = f2bf(r < 64 ? aw1[r * 512 + c] : cw1[(r - 64) * 512 + c]); return; }
    i -= 65536;
    if (i < 8192) { int r = i >> 6, c = i & 63;
        w2s[i] = f2bf(r < 64 ? aw2[r * 64 + c] : cw2[(r - 64) * 64 + c]); return; }
    i -= 8192;
    if (i < 13312) { int r = i >> 6, c = i & 63;
        w3s[i] = f2bf(r < 200 ? aw3[r * 64 + c] : 0.f); return; }
    i -= 13312;
    if (i < 128) { b1c[i] = i < 64 ? ab1[i] : cb1[i - 64]; return; }
    i -= 128;
    if (i < 128) { b2c[i] = i < 64 ? ab2[i] : cb2[i - 64]; return; }
    i -= 128;
    if (i < 208) { b3s[i] = i < 200 ? ab3[i] : 0.f; return; }
}

__global__ void f2b_kernel(const float* __restrict__ s, unsigned short* __restrict__ d, int n) {
    int i = (blockIdx.x * 256 + threadIdx.x) * 4;
    if (i < n) {
        float4 v = *(const float4*)(s + i);
        ushort4 o;
        o.x = f2bf(v.x); o.y = f2bf(v.y); o.z = f2bf(v.z); o.w = f2bf(v.w);
        *(ushort4*)(d + i) = o;
    }
}

__global__ void copy_actions(const int* __restrict__ a, float* __restrict__ o, int n) {
    int i = blockIdx.x * 256 + threadIdx.x;
    if (i < n) o[i] = (float)a[i];
}

extern "C" void kernel_launch(void* const* d_in, const int* in_sizes, int n_in,
                              void* d_out, int out_size, void* d_ws, size_t ws_size,
                              hipStream_t stream)
{
    const float* images = (const float*)d_in[0];
    const int*   actions = (const int*)d_in[1];
    const float* enc_w1 = (const float*)d_in[2];
    const float* enc_b1 = (const float*)d_in[3];
    const float* enc_w2 = (const float*)d_in[4];
    const float* enc_b2 = (const float*)d_in[5];
    const float* gru_wih = (const float*)d_in[6];
    const float* gru_bih = (const float*)d_in[7];
    const float* gru_whh = (const float*)d_in[8];
    const float* gru_bhh = (const float*)d_in[9];
    const float* act_w1 = (const float*)d_in[10];
    const float* act_b1 = (const float*)d_in[11];
    const float* act_w2 = (const float*)d_in[12];
    const float* act_b2 = (const float*)d_in[13];
    const float* act_w3 = (const float*)d_in[14];
    const float* act_b3 = (const float*)d_in[15];
    const float* cri_w1 = (const float*)d_in[16];
    const float* cri_b1 = (const float*)d_in[17];
    const float* cri_w2 = (const float*)d_in[18];
    const float* cri_b2 = (const float*)d_in[19];
    const float* cri_w3 = (const float*)d_in[20];
    const float* cri_b3 = (const float*)d_in[21];

    char* ws = (char*)d_ws;
    unsigned short* imgb = (unsigned short*)ws;                    // 64MB, dead after enc1
    __half*         xg   = (__half*)ws;                            // 48MB, written by gemm3
    unsigned short* hbA  = (unsigned short*)(ws + 67108864);       // y1 (16MB)
    unsigned short* hbB  = (unsigned short*)(ws + 83886080);       // x  (16MB)
    unsigned short* w1b  = (unsigned short*)(ws + 100663296);
    unsigned short* w2b  = (unsigned short*)(ws + 102760448);
    unsigned short* wihb = (unsigned short*)(ws + 103284736);
    unsigned short* whhb = (unsigned short*)(ws + 104857600);
    unsigned short* w1c  = (unsigned short*)(ws + 106430464);      // [128,512]
    unsigned short* w2s  = (unsigned short*)(ws + 106561536);      // [128,64]
    unsigned short* w3s  = (unsigned short*)(ws + 106577920);      // [208,64]
    float*          b1c  = (float*)(ws + 106604544);
    float*          b2c  = (float*)(ws + 106605056);
    float*          b3s  = (float*)(ws + 106605568);
    unsigned short* u1g  = (unsigned short*)(ws + 109051904);      // [B,128] 4MB
    unsigned short* u2g  = (unsigned short*)(ws + 113246208);      // [B,128] 4MB

    float* out_act = (float*)d_out;
    float* out_lp  = out_act + (size_t)BB * TT;
    float* out_ent = out_lp  + (size_t)BB * TT;
    float* out_v   = out_ent + (size_t)BB * TT;

    dim3 blk(256);

    f2b_kernel<<<(BB * DIMG / 4 + 255) / 256, blk, 0, stream>>>(images, imgb, BB * DIMG);
    f2b_kernel<<<(512 * DIMG / 4 + 255) / 256, blk, 0, stream>>>(enc_w1, w1b, 512 * DIMG);
    f2b_kernel<<<(512 * 512 / 4 + 255) / 256, blk, 0, stream>>>(enc_w2, w2b, 512 * 512);
    f2b_kernel<<<(3 * HH * HH / 4 + 255) / 256, blk, 0, stream>>>(gru_wih, wihb, 3 * HH * HH);
    f2b_kernel<<<(3 * HH * HH / 4 + 255) / 256, blk, 0, stream>>>(gru_whh, whhb, 3 * HH * HH);
    prep_heads<<<(87504 + 255) / 256, blk, 0, stream>>>(
        act_w1, cri_w1, act_w2, cri_w2, act_w3,
        act_b1, cri_b1, act_b2, cri_b2, act_b3,
        w1c, w2s, w3s, b1c, b2c, b3s);

    gemm_bt_mfma<1, 1><<<dim3(BB / 128, 4), blk, 0, stream>>>(imgb, w1b, enc_b1, hbA, BB, 512, DIMG);
    gemm_bt_mfma<0, 1><<<dim3(BB / 128, 4), blk, 0, stream>>>(hbA, w2b, enc_b2, hbB, BB, 512, HH);
    gemm_bt_mfma<0, 2><<<dim3(BB / 128, 12), blk, 0, stream>>>(hbB, wihb, gru_bih, xg, BB, 1536, HH);

    copy_actions<<<(BB * TT + 255) / 256, blk, 0, stream>>>(actions, out_act, BB * TT);

    persistent_gru<<<256, 512, 0, stream>>>(xg, whhb, gru_bhh,
        w1c, w2s, w3s, b1c, b2c, b3s, cri_w3, cri_b3, actions,
        u1g, u2g, out_lp, out_ent, out_v);
}

// Round 6
// 1522.793 us; speedup vs baseline: 2.1709x; 2.1709x over previous
//
#include <hip/hip_runtime.h>
#include <hip/hip_fp16.h>
#include <cstddef>
#include <cstdint>

#define BB 16384
#define DIMG 2048
#define HH 512
#define VOCAB 200
#define TT 20

using frag16 = __attribute__((ext_vector_type(8))) short;   // 8 x bf16 (4 VGPRs)
using f32x4v = __attribute__((ext_vector_type(4))) float;   // MFMA accumulator

#define MFMA16(a, b, c) __builtin_amdgcn_mfma_f32_16x16x32_bf16((a), (b), (c), 0, 0, 0)

__device__ __forceinline__ float bf2f(unsigned short u) {
    union { unsigned int i; float f; } c; c.i = ((unsigned int)u) << 16; return c.f;
}
__device__ __forceinline__ unsigned short f2bf(float f) {
    union { float f; unsigned int i; } c; c.f = f;
    unsigned int u = c.i;
    u = (u + 0x7FFFu + ((u >> 16) & 1u)) >> 16;   // RTNE
    return (unsigned short)u;
}
__device__ __forceinline__ float sigf(float x) { return 1.f / (1.f + __expf(-x)); }
__device__ __forceinline__ float ftanh(float x) {
    return 1.f - 2.f / (1.f + __expf(2.f * x));   // saturates correctly at +-inf
}
// async global->LDS, 16B/lane; LDS dest = wave-uniform base + lane*16
__device__ __forceinline__ void gload16(const void* g, void* l) {
    __builtin_amdgcn_global_load_lds(
        (__attribute__((address_space(1))) void*)g,
        (__attribute__((address_space(3))) void*)l, 16, 0, 0);
}

// ---------------------------------------------------------------------------
// bf16 MFMA GEMM for encoder: C = act(A[M,K] @ W[N,K]^T + bias).
// OM: 0=f32, 1=bf16, 2=f16 output.
// ---------------------------------------------------------------------------
template<int ACT, int OM>
__global__ __launch_bounds__(256) void gemm_bt_mfma(
    const unsigned short* __restrict__ A, const unsigned short* __restrict__ W,
    const float* __restrict__ bias, void* __restrict__ Cv, int M, int N, int K)
{
    __shared__ unsigned short As[128 * 32];
    __shared__ unsigned short Ws[128 * 32];
    const int t = threadIdx.x;
    const int lane = t & 63, w = t >> 6;
    const int bm = blockIdx.x, bn = blockIdx.y;
    const int wm = (w >> 1) * 64, wn = (w & 1) * 64;

    f32x4v acc[4][4];
    #pragma unroll
    for (int i = 0; i < 4; ++i)
        #pragma unroll
        for (int j = 0; j < 4; ++j)
            #pragma unroll
            for (int r = 0; r < 4; ++r) acc[i][j][r] = 0.f;

    const unsigned short* Ag  = A + (size_t)(bm * 128 + (t >> 2)) * K + (t & 3) * 8;
    const unsigned short* Ag2 = A + (size_t)(bm * 128 + 64 + (t >> 2)) * K + (t & 3) * 8;
    const unsigned short* Wg  = W + (size_t)(bn * 128 + (t >> 2)) * K + (t & 3) * 8;
    const unsigned short* Wg2 = W + (size_t)(bn * 128 + 64 + (t >> 2)) * K + (t & 3) * 8;
    char* AsB = (char*)As; char* WsB = (char*)Ws;

    const int kIters = K >> 5;
    for (int ki = 0; ki < kIters; ++ki) {
        const int k0 = ki * 32;
        gload16(Ag  + k0, AsB + w * 1024);
        gload16(Ag2 + k0, AsB + 4096 + w * 1024);
        gload16(Wg  + k0, WsB + w * 1024);
        gload16(Wg2 + k0, WsB + 4096 + w * 1024);
        __syncthreads();
        frag16 af[4], bf[4];
        #pragma unroll
        for (int i = 0; i < 4; ++i) {
            af[i] = *(const frag16*)(AsB + (wm + i * 16 + (lane & 15)) * 64 + (lane >> 4) * 16);
            bf[i] = *(const frag16*)(WsB + (wn + i * 16 + (lane & 15)) * 64 + (lane >> 4) * 16);
        }
        #pragma unroll
        for (int i = 0; i < 4; ++i)
            #pragma unroll
            for (int j = 0; j < 4; ++j)
                acc[i][j] = MFMA16(af[i], bf[j], acc[i][j]);
        __syncthreads();
    }

    #pragma unroll
    for (int j = 0; j < 4; ++j) {
        const int gn = bn * 128 + wn + j * 16 + (lane & 15);
        const float bv = bias[gn];
        #pragma unroll
        for (int i = 0; i < 4; ++i) {
            #pragma unroll
            for (int r = 0; r < 4; ++r) {
                const size_t gm = (size_t)(bm * 128 + wm + i * 16 + (lane >> 4) * 4 + r);
                float v = acc[i][j][r] + bv;
                if (ACT == 1) v = fmaxf(v, 0.f);
                if (OM == 0)      ((float*)Cv)[gm * N + gn] = v;
                else if (OM == 1) ((unsigned short*)Cv)[gm * N + gn] = f2bf(v);
                else              ((__half*)Cv)[gm * N + gn] = __float2half(v);
            }
        }
    }
}

// ---------------------------------------------------------------------------
// GRU step body, tile 64 rows x 64 h-cols, BK=64. 256 threads, 4 waves.
// K-loop: A(h) 8KB + W(whh,3 gates) 24KB staged via DMA (kk-half-split).
// Epilogue: xg (3x8KB fp16) + h_old (8KB) DMA'd into the SAME 32KB region,
// gate math from LDS, h_out repacked in LDS -> coalesced dwordx4 stores.
// ---------------------------------------------------------------------------
__device__ __forceinline__ void gru_body(
    unsigned short* lds,
    const unsigned short* __restrict__ hb, unsigned short* __restrict__ hob,
    const unsigned short* __restrict__ whhb, const float* __restrict__ bhh,
    const __half* __restrict__ xg, int bm, int bn, int t)
{
    char* L = (char*)lds;
    const int lane = t & 63, w = t >> 6;
    const int q = lane >> 4, m = lane & 15;

    f32x4v acc[3][4];
    #pragma unroll
    for (int g = 0; g < 3; ++g)
        #pragma unroll
        for (int j = 0; j < 4; ++j)
            #pragma unroll
            for (int r = 0; r < 4; ++r) acc[g][j][r] = 0.f;

    // ---- K-loop staging addresses ----
    const unsigned short* Ag = hb + (size_t)(bm * 64 + (t >> 2)) * HH + (t & 3) * 8;
    const unsigned short* Wg0 = whhb + (size_t)(0 * HH + bn * 64 + (t >> 2)) * HH + (t & 3) * 8;
    const unsigned short* Wg1 = whhb + (size_t)(1 * HH + bn * 64 + (t >> 2)) * HH + (t & 3) * 8;
    const unsigned short* Wg2 = whhb + (size_t)(2 * HH + bn * 64 + (t >> 2)) * HH + (t & 3) * 8;

    for (int ki = 0; ki < 8; ++ki) {
        const int k0 = ki * 64;
        gload16(Ag + k0,       L + w * 1024);
        gload16(Ag + k0 + 32,  L + 4096 + w * 1024);
        gload16(Wg0 + k0,      L + 8192 + w * 1024);
        gload16(Wg0 + k0 + 32, L + 8192 + 12288 + w * 1024);
        gload16(Wg1 + k0,      L + 8192 + 4096 + w * 1024);
        gload16(Wg1 + k0 + 32, L + 8192 + 12288 + 4096 + w * 1024);
        gload16(Wg2 + k0,      L + 8192 + 8192 + w * 1024);
        gload16(Wg2 + k0 + 32, L + 8192 + 12288 + 8192 + w * 1024);
        __syncthreads();
        #pragma unroll
        for (int kk = 0; kk < 2; ++kk) {
            frag16 af = *(const frag16*)(L + kk * 4096 + (w * 16 + m) * 64 + q * 16);
            #pragma unroll
            for (int g = 0; g < 3; ++g)
                #pragma unroll
                for (int j = 0; j < 4; ++j) {
                    frag16 bf = *(const frag16*)(L + 8192 + kk * 12288 + g * 4096 + (j * 16 + m) * 64 + q * 16);
                    acc[g][j] = MFMA16(af, bf, acc[g][j]);
                }
        }
        __syncthreads();
    }

    // ---- epilogue DMA: xg tiles at L+g*8192, h_old at L+24576 ----
    {
        const __half* Xg = xg + (size_t)(bm * 64 + (t >> 3)) * (3 * HH) + bn * 64 + (t & 7) * 8;
        #pragma unroll
        for (int c = 0; c < 6; ++c) {
            const int g = c >> 1, rh = c & 1;
            gload16(Xg + (size_t)rh * 32 * (3 * HH) + g * HH, L + g * 8192 + rh * 4096 + w * 1024);
        }
        const unsigned short* Hg = hb + (size_t)(bm * 64 + (t >> 3)) * HH + bn * 64 + (t & 7) * 8;
        gload16(Hg,                       L + 24576 + w * 1024);
        gload16(Hg + (size_t)32 * HH,     L + 24576 + 4096 + w * 1024);
    }
    __syncthreads();

    float br[4], bz[4], bnn[4];
    #pragma unroll
    for (int j = 0; j < 4; ++j) {
        const int gc = bn * 64 + j * 16 + m;
        br[j] = bhh[gc]; bz[j] = bhh[HH + gc]; bnn[j] = bhh[2 * HH + gc];
    }

    unsigned short hv[4][4];
    #pragma unroll
    for (int r = 0; r < 4; ++r) {
        const int row = w * 16 + q * 4 + r;
        #pragma unroll
        for (int j = 0; j < 4; ++j) {
            const int col2 = (j * 16 + m) * 2;
            const float xr = __half2float(*(const __half*)(L + row * 128 + col2));
            const float xz = __half2float(*(const __half*)(L + 8192 + row * 128 + col2));
            const float xn = __half2float(*(const __half*)(L + 16384 + row * 128 + col2));
            const float ho = bf2f(*(const unsigned short*)(L + 24576 + row * 128 + col2));
            const float rg = sigf(xr + acc[0][j][r] + br[j]);
            const float zg = sigf(xz + acc[1][j][r] + bz[j]);
            const float ng = ftanh(xn + rg * (acc[2][j][r] + bnn[j]));
            hv[r][j] = f2bf((1.f - zg) * ng + zg * ho);
        }
    }
    __syncthreads();   // all epilogue LDS reads done; reuse h_old area for h_out
    #pragma unroll
    for (int r = 0; r < 4; ++r) {
        const int row = w * 16 + q * 4 + r;
        #pragma unroll
        for (int j = 0; j < 4; ++j)
            *(unsigned short*)(L + 24576 + row * 128 + (j * 16 + m) * 2) = hv[r][j];
    }
    __syncthreads();
    // coalesced store: thread t -> row t>>2, 32B at col (t&3)*16
    {
        const int sr = t >> 2, sc = (t & 3) * 16;
        uint4 v0 = *(const uint4*)(L + 24576 + sr * 128 + sc * 2);
        uint4 v1 = *(const uint4*)(L + 24576 + sr * 128 + sc * 2 + 16);
        unsigned short* dst = hob + (size_t)(bm * 64 + sr) * HH + bn * 64 + sc;
        *(uint4*)dst = v0;
        *(uint4*)(dst + 8) = v1;
    }
}

// ---------------------------------------------------------------------------
// Heads body (round-4 proven): 32 batch rows per block, BK=64 phase-1 staging.
// ---------------------------------------------------------------------------
__device__ __forceinline__ void heads_body(
    unsigned short* lds, const unsigned short* __restrict__ hxb,
    const unsigned short* __restrict__ w1c, const unsigned short* __restrict__ w2s,
    const unsigned short* __restrict__ w3s,
    const float* __restrict__ b1c, const float* __restrict__ b2c,
    const float* __restrict__ b3s,
    const float* __restrict__ cw3, const float* __restrict__ cb3,
    const int* __restrict__ actions,
    float* __restrict__ out_lp, float* __restrict__ out_ent,
    float* __restrict__ out_v, int tstep, int hblk, int t)
{
    char* sH = (char*)lds;              // 4 KB: two 2 KB kk-halves [32][64B]
    char* sW = (char*)lds + 4096;       // 16 KB: two 8 KB kk-halves [128][64B]
    unsigned short* u1 = lds;           // aliased after phase 1: [32][136]
    const int lane = t & 63, w = t >> 6;
    const int q = lane >> 4, m = lane & 15;
    const int row0 = hblk * 32;
    const int ri = (w & 1) * 16, ch = (w >> 1) * 64;

    // ---------------- phase 1: u1 = tanh(h @ w1c^T + b1c) ----------------
    f32x4v acc[4];
    #pragma unroll
    for (int j = 0; j < 4; ++j)
        #pragma unroll
        for (int r = 0; r < 4; ++r) acc[j][r] = 0.f;

    const unsigned short* Hrow = hxb + (size_t)(row0 + ((t >> 2) & 31)) * HH
                                 + (t >> 7) * 32 + (t & 3) * 8;
    const unsigned short* Wrow[4]; int WldsOff[4];
    #pragma unroll
    for (int c = 0; c < 4; ++c) {
        const int kk = c & 1, rb = (c >> 1) * 64;
        Wrow[c] = w1c + (size_t)(rb + (t >> 2)) * HH + kk * 32 + (t & 3) * 8;
        WldsOff[c] = kk * 8192 + rb * 64;
    }

    for (int ki = 0; ki < 8; ++ki) {
        const int k0 = ki * 64;
        gload16(Hrow + k0, sH + w * 1024);
        #pragma unroll
        for (int c = 0; c < 4; ++c)
            gload16(Wrow[c] + k0, sW + WldsOff[c] + w * 1024);
        __syncthreads();
        #pragma unroll
        for (int kk = 0; kk < 2; ++kk) {
            frag16 af = *(const frag16*)(sH + kk * 2048 + (ri + m) * 64 + q * 16);
            #pragma unroll
            for (int j = 0; j < 4; ++j) {
                frag16 bf = *(const frag16*)(sW + kk * 8192 + (ch + j * 16 + m) * 64 + q * 16);
                acc[j] = MFMA16(af, bf, acc[j]);
            }
        }
        __syncthreads();
    }
    #pragma unroll
    for (int j = 0; j < 4; ++j) {
        const int col = ch + j * 16 + m;
        const float bv = b1c[col];
        #pragma unroll
        for (int r = 0; r < 4; ++r)
            u1[(ri + q * 4 + r) * 136 + col] = f2bf(ftanh(acc[j][r] + bv));
    }
    __syncthreads();

    // ---------------- phase 2: u2 (actor ch=0 / critic ch=64) ----------------
    f32x4v acc2[4];
    #pragma unroll
    for (int j = 0; j < 4; ++j)
        #pragma unroll
        for (int r = 0; r < 4; ++r) acc2[j][r] = 0.f;
    #pragma unroll
    for (int kk = 0; kk < 2; ++kk) {
        frag16 af2 = *(const frag16*)(u1 + (ri + m) * 136 + ch + kk * 32 + q * 8);
        #pragma unroll
        for (int j = 0; j < 4; ++j) {
            frag16 bf2 = *(const frag16*)(w2s + (size_t)(ch + j * 16 + m) * 64 + kk * 32 + q * 8);
            acc2[j] = MFMA16(af2, bf2, acc2[j]);
        }
    }
    __syncthreads();
    #pragma unroll
    for (int j = 0; j < 4; ++j) {
        const int col = ch + j * 16 + m;
        const float bv = b2c[col];
        #pragma unroll
        for (int r = 0; r < 4; ++r)
            u1[(ri + q * 4 + r) * 136 + col] = f2bf(ftanh(acc2[j][r] + bv));
    }
    __syncthreads();

    // ---------------- phase 3 ----------------
    if (w < 2) {
        f32x4v acc3[13];
        #pragma unroll
        for (int j = 0; j < 13; ++j)
            #pragma unroll
            for (int r = 0; r < 4; ++r) acc3[j][r] = 0.f;
        #pragma unroll
        for (int kk = 0; kk < 2; ++kk) {
            frag16 af3 = *(const frag16*)(u1 + (w * 16 + m) * 136 + kk * 32 + q * 8);
            #pragma unroll
            for (int j = 0; j < 13; ++j) {
                frag16 bf3 = *(const frag16*)(w3s + (size_t)(j * 16 + m) * 64 + kk * 32 + q * 8);
                acc3[j] = MFMA16(af3, bf3, acc3[j]);
            }
        }
        float bcol[13];
        #pragma unroll
        for (int j = 0; j < 13; ++j) bcol[j] = b3s[j * 16 + m];
        const bool vlast = (m < 8);
        #pragma unroll
        for (int r = 0; r < 4; ++r) {
            const int gr = row0 + w * 16 + 4 * q + r;
            const int a = actions[(size_t)gr * TT + tstep];
            float lg[13], mx = -1e30f;
            #pragma unroll
            for (int j = 0; j < 13; ++j) {
                float v = acc3[j][r] + bcol[j];
                lg[j] = (j < 12 || vlast) ? v : -1e30f;
                mx = fmaxf(mx, lg[j]);
            }
            #pragma unroll
            for (int o = 1; o < 16; o <<= 1) mx = fmaxf(mx, __shfl_xor(mx, o));
            float s1 = 0.f, s2 = 0.f, sel = 0.f;
            #pragma unroll
            for (int j = 0; j < 13; ++j) {
                float e = __expf(lg[j] - mx);
                s1 += e; s2 += e * lg[j];
                sel += (j * 16 + m == a) ? lg[j] : 0.f;
            }
            #pragma unroll
            for (int o = 1; o < 16; o <<= 1) {
                s1 += __shfl_xor(s1, o); s2 += __shfl_xor(s2, o); sel += __shfl_xor(sel, o);
            }
            const float lse = mx + __logf(s1);
            if (m == 0) {
                out_lp[(size_t)gr * TT + tstep]  = sel - lse;
                out_ent[(size_t)gr * TT + tstep] = lse - s2 / s1;
            }
        }
    } else {
        const int row = (w - 2) * 16 + m;
        const unsigned short* u2row = u1 + row * 136 + 64 + q * 16;
        float pv = 0.f;
        #pragma unroll
        for (int kk = 0; kk < 16; ++kk)
            pv += bf2f(u2row[kk]) * cw3[q * 16 + kk];
        pv += __shfl_xor(pv, 16);
        pv += __shfl_xor(pv, 32);
        if (q == 0) out_v[(size_t)(row0 + row) * TT + tstep] = pv + cb3[0];
    }
}

// ---------------------------------------------------------------------------
// Fused per-step launch: blocks 0..2047 = gru_t ; blocks 2048..2559 = heads_{t-1}.
// gru block order: bm fast (bm = b & 255) so same-XCD blocks share h rows (L2).
// ---------------------------------------------------------------------------
__global__ __launch_bounds__(256, 4) void step_fused(
    const unsigned short* __restrict__ hin, unsigned short* __restrict__ hout,
    const unsigned short* __restrict__ whhb, const float* __restrict__ bhh,
    const __half* __restrict__ xg,
    const unsigned short* __restrict__ w1c, const unsigned short* __restrict__ w2s,
    const unsigned short* __restrict__ w3s,
    const float* __restrict__ b1c, const float* __restrict__ b2c,
    const float* __restrict__ b3s,
    const float* __restrict__ cw3, const float* __restrict__ cb3,
    const int* __restrict__ actions,
    float* __restrict__ out_lp, float* __restrict__ out_ent,
    float* __restrict__ out_v, int hstep)
{
    __shared__ unsigned short lds[16384];   // 32 KB
    const int b = blockIdx.x;
    if (b < 2048) {
        gru_body(lds, hin, hout, whhb, bhh, xg, b & 255, b >> 8, threadIdx.x);
    } else if (hstep >= 0) {
        heads_body(lds, hin, w1c, w2s, w3s, b1c, b2c, b3s, cw3, cb3,
                   actions, out_lp, out_ent, out_v, hstep, b - 2048, threadIdx.x);
    }
}

__global__ __launch_bounds__(256) void heads_tail(
    const unsigned short* __restrict__ hx,
    const unsigned short* __restrict__ w1c, const unsigned short* __restrict__ w2s,
    const unsigned short* __restrict__ w3s,
    const float* __restrict__ b1c, const float* __restrict__ b2c,
    const float* __restrict__ b3s,
    const float* __restrict__ cw3, const float* __restrict__ cb3,
    const int* __restrict__ actions,
    float* __restrict__ out_lp, float* __restrict__ out_ent,
    float* __restrict__ out_v, int tstep)
{
    __shared__ unsigned short lds[10240];   // 20 KB
    heads_body(lds, hx, w1c, w2s, w3s, b1c, b2c, b3s, cw3, cb3,
               actions, out_lp, out_ent, out_v, tstep, blockIdx.x, threadIdx.x);
}

// ---------------------------------------------------------------------------
// One-time packing of head weights/biases.
// ---------------------------------------------------------------------------
__global__ void prep_heads(
    const float* __restrict__ aw1, const float* __restrict__ cw1,
    const float* __restrict__ aw2, const float* __restrict__ cw2,
    const float* __restrict__ aw3,
    const float* __restrict__ ab1, const float* __restrict__ cb1,
    const float* __restrict__ ab2, const float* __restrict__ cb2,
    const float* __restrict__ ab3,
    unsigned short* __restrict__ w1c, unsigned short* __restrict__ w2s,
    unsigned short* __restrict__ w3s,
    float* __restrict__ b1c, float* __restrict__ b2c, float* __restrict__ b3s)
{
    int i = blockIdx.x * 256 + threadIdx.x;
    if (i < 65536) { int r = i >> 9, c = i & 511;
        w1c[i] = f2bf(r < 64 ? aw1[r * 512 + c] : cw1[(r - 64) * 512 + c]); return; }
    i -= 65536;
    if (i < 8192) { int r = i >> 6, c = i & 63;
        w2s[i] = f2bf(r < 64 ? aw2[r * 64 + c] : cw2[(r - 64) * 64 + c]); return; }
    i -= 8192;
    if (i < 13312) { int r = i >> 6, c = i & 63;
        w3s[i] = f2bf(r < 200 ? aw3[r * 64 + c] : 0.f); return; }
    i -= 13312;
    if (i < 128) { b1c[i] = i < 64 ? ab1[i] : cb1[i - 64]; return; }
    i -= 128;
    if (i < 128) { b2c[i] = i < 64 ? ab2[i] : cb2[i - 64]; return; }
    i -= 128;
    if (i < 208) { b3s[i] = i < 200 ? ab3[i] : 0.f; return; }
}

__global__ void f2b_kernel(const float* __restrict__ s, unsigned short* __restrict__ d, int n) {
    int i = (blockIdx.x * 256 + threadIdx.x) * 4;
    if (i < n) {
        float4 v = *(const float4*)(s + i);
        ushort4 o;
        o.x = f2bf(v.x); o.y = f2bf(v.y); o.z = f2bf(v.z); o.w = f2bf(v.w);
        *(ushort4*)(d + i) = o;
    }
}

__global__ void copy_actions(const int* __restrict__ a, float* __restrict__ o, int n) {
    int i = blockIdx.x * 256 + threadIdx.x;
    if (i < n) o[i] = (float)a[i];
}

extern "C" void kernel_launch(void* const* d_in, const int* in_sizes, int n_in,
                              void* d_out, int out_size, void* d_ws, size_t ws_size,
                              hipStream_t stream)
{
    const float* images = (const float*)d_in[0];
    const int*   actions = (const int*)d_in[1];
    const float* enc_w1 = (const float*)d_in[2];
    const float* enc_b1 = (const float*)d_in[3];
    const float* enc_w2 = (const float*)d_in[4];
    const float* enc_b2 = (const float*)d_in[5];
    const float* gru_wih = (const float*)d_in[6];
    const float* gru_bih = (const float*)d_in[7];
    const float* gru_whh = (const float*)d_in[8];
    const float* gru_bhh = (const float*)d_in[9];
    const float* act_w1 = (const float*)d_in[10];
    const float* act_b1 = (const float*)d_in[11];
    const float* act_w2 = (const float*)d_in[12];
    const float* act_b2 = (const float*)d_in[13];
    const float* act_w3 = (const float*)d_in[14];
    const float* act_b3 = (const float*)d_in[15];
    const float* cri_w1 = (const float*)d_in[16];
    const float* cri_b1 = (const float*)d_in[17];
    const float* cri_w2 = (const float*)d_in[18];
    const float* cri_b2 = (const float*)d_in[19];
    const float* cri_w3 = (const float*)d_in[20];
    const float* cri_b3 = (const float*)d_in[21];

    char* ws = (char*)d_ws;
    unsigned short* imgb = (unsigned short*)ws;                    // 64MB, dead after enc1
    __half*         xg   = (__half*)ws;                            // 48MB, written by gemm3
    unsigned short* hbA  = (unsigned short*)(ws + 67108864);       // y1 / h ping (16MB)
    unsigned short* hbB  = (unsigned short*)(ws + 83886080);       // x  / h pong (16MB)
    unsigned short* w1b  = (unsigned short*)(ws + 100663296);
    unsigned short* w2b  = (unsigned short*)(ws + 102760448);
    unsigned short* wihb = (unsigned short*)(ws + 103284736);
    unsigned short* whhb = (unsigned short*)(ws + 104857600);
    unsigned short* w1c  = (unsigned short*)(ws + 106430464);      // [128,512]
    unsigned short* w2s  = (unsigned short*)(ws + 106561536);      // [128,64]
    unsigned short* w3s  = (unsigned short*)(ws + 106577920);      // [208,64]
    float*          b1c  = (float*)(ws + 106604544);
    float*          b2c  = (float*)(ws + 106605056);
    float*          b3s  = (float*)(ws + 106605568);

    float* out_act = (float*)d_out;
    float* out_lp  = out_act + (size_t)BB * TT;
    float* out_ent = out_lp  + (size_t)BB * TT;
    float* out_v   = out_ent + (size_t)BB * TT;

    dim3 blk(256);

    f2b_kernel<<<(BB * DIMG / 4 + 255) / 256, blk, 0, stream>>>(images, imgb, BB * DIMG);
    f2b_kernel<<<(512 * DIMG / 4 + 255) / 256, blk, 0, stream>>>(enc_w1, w1b, 512 * DIMG);
    f2b_kernel<<<(512 * 512 / 4 + 255) / 256, blk, 0, stream>>>(enc_w2, w2b, 512 * 512);
    f2b_kernel<<<(3 * HH * HH / 4 + 255) / 256, blk, 0, stream>>>(gru_wih, wihb, 3 * HH * HH);
    f2b_kernel<<<(3 * HH * HH / 4 + 255) / 256, blk, 0, stream>>>(gru_whh, whhb, 3 * HH * HH);
    prep_heads<<<(87504 + 255) / 256, blk, 0, stream>>>(
        act_w1, cri_w1, act_w2, cri_w2, act_w3,
        act_b1, cri_b1, act_b2, cri_b2, act_b3,
        w1c, w2s, w3s, b1c, b2c, b3s);

    // encoder + input-gate GEMMs; xg stored fp16
    gemm_bt_mfma<1, 1><<<dim3(BB / 128, 4), blk, 0, stream>>>(imgb, w1b, enc_b1, hbA, BB, 512, DIMG);
    gemm_bt_mfma<0, 1><<<dim3(BB / 128, 4), blk, 0, stream>>>(hbA, w2b, enc_b2, hbB, BB, 512, HH);
    gemm_bt_mfma<0, 2><<<dim3(BB / 128, 12), blk, 0, stream>>>(hbB, wihb, gru_bih, xg, BB, 1536, HH);

    // h0 = 0 in hbA (its y1 contents are dead after enc2)
    hipMemsetAsync(hbA, 0, (size_t)BB * HH * 2, stream);
    copy_actions<<<(BB * TT + 255) / 256, blk, 0, stream>>>(actions, out_act, BB * TT);

    for (int t = 0; t < TT; ++t) {
        const unsigned short* hin = (t & 1) ? hbB : hbA;
        unsigned short*      hout = (t & 1) ? hbA : hbB;
        step_fused<<<2560, blk, 0, stream>>>(hin, hout, whhb, gru_bhh, xg,
            w1c, w2s, w3s, b1c, b2c, b3s, cri_w3, cri_b3, actions,
            out_lp, out_ent, out_v, t - 1);
    }
    heads_tail<<<512, blk, 0, stream>>>((TT & 1) ? hbB : hbA, w1c, w2s, w3s,
        b1c, b2c, b3s, cri_w3, cri_b3, actions, out_lp, out_ent, out_v, TT - 1);
}